// Round 9
// baseline (265.654 us; speedup 1.0000x reference)
//
#include <hip/hip_runtime.h>

// Problem constants (B,T,C,NH fixed by the reference).
constexpr int kB  = 8;
constexpr int kT  = 1024;
constexpr int kC  = 768;
constexpr int kNH = 12;
constexpr int kHD = 64;          // C/NH
constexpr int kM  = kB * kT;     // 8192 rows
constexpr int k3C = 3 * kC;      // 2304

using bf16x8 = __attribute__((ext_vector_type(8))) __bf16;
using f32x4  = __attribute__((ext_vector_type(4))) float;

__device__ __forceinline__ float bf2f(unsigned short u) {
    union { unsigned int i; float f; } v;
    v.i = ((unsigned int)u) << 16;
    return v.f;
}

// fp32 -> bf16 round-to-nearest-even.
__device__ __forceinline__ unsigned short f2bf(float f) {
    union { float f; unsigned int u; } v; v.f = f;
    unsigned int r = v.u + 0x7fffu + ((v.u >> 16) & 1u);
    return (unsigned short)(r >> 16);
}

// Async global->LDS, 16 B/lane. LDS arg must be the wave-uniform base; HW
// writes lane i at base + i*16 (m104/m108).
__device__ __forceinline__ void async16(const void* g, void* l) {
    __builtin_amdgcn_global_load_lds(
        (__attribute__((address_space(1))) void*)g,
        (__attribute__((address_space(3))) void*)l, 16, 0, 0);
}

// Explicit LDS-DMA drain (round-5 determinism fix — keep).
// imm: vmcnt[3:0]=0 (+[15:14]=0), expcnt[6:4]=7, lgkmcnt[11:8]=15.
__device__ __forceinline__ void wait_vm0() {
    __builtin_amdgcn_s_waitcnt(0x0F70);
}

// ---------------- pre-passes ----------------

// fp32 -> bf16 elementwise (n divisible by 4*256).
__global__ __launch_bounds__(256) void cvt_bf16_kernel(
    const float* __restrict__ in, unsigned short* __restrict__ out)
{
    const int i = blockIdx.x * 256 + threadIdx.x;
    const float4 v = ((const float4*)in)[i];
    ushort4 o;
    o.x = f2bf(v.x); o.y = f2bf(v.y); o.z = f2bf(v.z); o.w = f2bf(v.w);
    ((ushort4*)out)[i] = o;
}

// W[K][N] fp32 -> Wt[N][K] bf16.  Grid (N/32, K/32), block 256 (32x8).
__global__ __launch_bounds__(256) void transpose_cvt_kernel(
    const float* __restrict__ W, unsigned short* __restrict__ Wt, int K, int N)
{
    __shared__ float tile[32][33];
    const int tx = threadIdx.x & 31, ty = threadIdx.x >> 5;
    const int n0 = blockIdx.x * 32, k0 = blockIdx.y * 32;
    #pragma unroll
    for (int i = 0; i < 4; ++i)
        tile[ty + i * 8][tx] = W[(size_t)(k0 + ty + i * 8) * N + n0 + tx];
    __syncthreads();
    #pragma unroll
    for (int i = 0; i < 4; ++i)
        Wt[(size_t)(n0 + ty + i * 8) * K + k0 + tx] = f2bf(tile[tx][ty + i * 8]);
}

// V columns of qkv -> VT[bh][d][t] (bf16).  One block = 64t x 64d of one
// (b,h).  Grid 96*16.
__global__ __launch_bounds__(256) void vtrans_kernel(
    const unsigned short* __restrict__ qkv, unsigned short* __restrict__ VT)
{
    __shared__ unsigned short tile[64][72];   // 144 B rows (16B-aligned)
    const int tid = threadIdx.x;
    const int bh = blockIdx.x >> 4;
    const int b = bh / kNH, h = bh % kNH;
    const int tt = (blockIdx.x & 15) * 64;
    const int row = tid >> 2;
    const int c0  = (tid & 3) * 16;
    const unsigned short* src =
        qkv + (size_t)(b * kT + tt + row) * k3C + 2 * kC + h * kHD + c0;
    *(uint4*)&tile[row][c0]     = *(const uint4*)src;
    *(uint4*)&tile[row][c0 + 8] = *(const uint4*)(src + 8);
    __syncthreads();
    const int d  = tid >> 2;
    const int t8 = (tid & 3) * 16;
    unsigned short tmp[16];
    #pragma unroll
    for (int i = 0; i < 16; ++i) tmp[i] = tile[t8 + i][d];
    unsigned short* dst = VT + ((size_t)bh * kHD + d) * kT + tt + t8;
    *(uint4*)dst       = *(uint4*)&tmp[0];
    *(uint4*)(dst + 8) = *(uint4*)&tmp[8];
}

// ---------------- MFMA GEMM ----------------
// out[M,N] = A[M,K](bf16, row stride lda) @ Bt[N,K](bf16)^T + bias(fp32).
// Round-9: 128x64 tile (was 128x128), BK=64, 256 threads / 4 waves, each
// wave a 64x32 sub-tile (acc 4x2).  Rationale: round-8 profile showed both
// GEMMs at ~76 us despite 3x FLOP difference -> concurrency-bound, not
// FLOP-bound (gemm2 grid was 1.5 blocks/CU).  128x64 gives gemm1 9.0 and
// gemm2 3.0 blocks/CU (uniform), LDS 24 KB -> 6 resident blocks/CU to
// cover the per-iteration stage->drain->barrier chain.
template<bool OUT_BF16>
__global__ __launch_bounds__(256) void gemm_mfma_kernel(
    const unsigned short* __restrict__ A, int lda,
    const unsigned short* __restrict__ Bt,
    const float* __restrict__ bias,
    void* __restrict__ outv, int N, int K)
{
    alignas(16) __shared__ unsigned short As[16 * 512];  // 16 KB
    alignas(16) __shared__ unsigned short Bs[8 * 512];   //  8 KB

    const int tid  = threadIdx.x;
    const int w    = tid >> 6;
    const int lane = tid & 63;
    const int wr = w >> 1, wc = w & 1;
    const int m0 = blockIdx.y * 128, n0 = blockIdx.x * 64;

    const int fr = lane & 15;            // row within 16-row subtile
    const int fk = (lane >> 4) * 8;      // k offset within 32-k subtile

    f32x4 acc[4][2];
    #pragma unroll
    for (int i = 0; i < 4; ++i)
        #pragma unroll
        for (int j = 0; j < 2; ++j) {
            f32x4 z = {0.f, 0.f, 0.f, 0.f};
            acc[i][j] = z;
        }

    for (int kt = 0; kt < K; kt += 64) {
        // A: 16 frags (ki*8+si), 4 per wave.
        #pragma unroll
        for (int t = 0; t < 4; ++t) {
            const int fa = w * 4 + t;
            const int ki = fa >> 3, si = fa & 7;
            const unsigned short* ga =
                A + (size_t)(m0 + si * 16 + fr) * lda + kt + ki * 32 + fk;
            async16(ga, &As[fa * 512]);          // wave-uniform LDS base
        }
        // B: 8 frags (ki*4+sj), 2 per wave.
        #pragma unroll
        for (int t = 0; t < 2; ++t) {
            const int fb = w * 2 + t;
            const int ki = fb >> 2, sj = fb & 3;
            const unsigned short* gb =
                Bt + (size_t)(n0 + sj * 16 + fr) * K + kt + ki * 32 + fk;
            async16(gb, &Bs[fb * 512]);
        }
        wait_vm0();
        __syncthreads();

        #pragma unroll
        for (int ki = 0; ki < 2; ++ki) {
            bf16x8 a[4], b[2];
            #pragma unroll
            for (int i = 0; i < 4; ++i)
                a[i] = *(const bf16x8*)&As[(ki * 8 + wr * 4 + i) * 512 + lane * 8];
            #pragma unroll
            for (int j = 0; j < 2; ++j)
                b[j] = *(const bf16x8*)&Bs[(ki * 4 + wc * 2 + j) * 512 + lane * 8];
            #pragma unroll
            for (int i = 0; i < 4; ++i)
                #pragma unroll
                for (int j = 0; j < 2; ++j)
                    acc[i][j] = __builtin_amdgcn_mfma_f32_16x16x32_bf16(
                        a[i], b[j], acc[i][j], 0, 0, 0);
        }
        __syncthreads();
    }

    // Epilogue.  C/D: col = lane&15, row = (lane>>4)*4 + reg.
    const int quad  = lane >> 4;
    const int col16 = lane & 15;
    float biasv[2];
    #pragma unroll
    for (int j = 0; j < 2; ++j)
        biasv[j] = bias[n0 + wc * 32 + j * 16 + col16];

    #pragma unroll
    for (int i = 0; i < 4; ++i) {
        #pragma unroll
        for (int r = 0; r < 4; ++r) {
            const int row = m0 + wr * 64 + i * 16 + quad * 4 + r;
            #pragma unroll
            for (int j = 0; j < 2; ++j) {
                const int col = n0 + wc * 32 + j * 16 + col16;
                const float v = acc[i][j][r] + biasv[j];
                if (OUT_BF16)
                    ((unsigned short*)outv)[(size_t)row * N + col] = f2bf(v);
                else
                    ((float*)outv)[(size_t)row * N + col] = v;
            }
        }
    }
}

// ---------------- MFMA flash attention (paired q-tiles) ----------------
// One block = q-tiles (15-pid, pid) of one (b,h): uniform 17-chunk cost.
// K/V dbuf prefetch, reg-Q, reg-softmax (rounds 6-8).
__global__ __launch_bounds__(256) void attn_mfma_kernel(
    const unsigned short* __restrict__ qkv,
    const unsigned short* __restrict__ VT,     // [96][64][1024]
    unsigned short* __restrict__ y)            // [8192][768]
{
    alignas(16) __shared__ unsigned short Kf[2][8 * 512];  // 16 KB
    alignas(16) __shared__ unsigned short Vf[2][8 * 512];  // 16 KB
    alignas(16) __shared__ unsigned short Pf[8 * 512];     // 8 KB, wave-private

    const int tid  = threadIdx.x;
    const int w    = tid >> 6;
    const int lane = tid & 63;
    const int quad = lane >> 4, l15 = lane & 15;
    const int bh  = blockIdx.x >> 3;
    const int b   = bh / kNH, h = bh % kNH;
    const int pid = blockIdx.x & 7;

    // Stage K frags (ksub=w) and V^T frags (nsub=w) for chunk kbase.
    auto stage = [&](int bufi, int kbase) {
        const unsigned short* gk = qkv +
            (size_t)(b * kT + kbase + w * 16 + l15) * k3C + kC + h * kHD + quad * 8;
        async16(gk,      &Kf[bufi][(w * 2 + 0) * 512]);
        async16(gk + 32, &Kf[bufi][(w * 2 + 1) * 512]);
        const unsigned short* gv = VT +
            ((size_t)bh * kHD + w * 16 + l15) * kT + kbase + quad * 8;
        async16(gv,      &Vf[bufi][(w * 2 + 0) * 512]);
        async16(gv + 32, &Vf[bufi][(w * 2 + 1) * 512]);
    };

    #pragma unroll 1
    for (int phase = 0; phase < 2; ++phase) {
        const int t0 = (phase == 0 ? (15 - pid) : pid) * 64;  // heavy first
        const int nchunks = t0 / 64 + 1;

        // WAR: all waves done reading K/V buffers from the previous phase
        // before we restage buffer 0. (Harmless extra barrier in phase 0.)
        __syncthreads();
        stage(0, 0);
        // Q staged once through Pf (wave-private region) -> registers.
        {
            const unsigned short* g0 = qkv +
                (size_t)(b * kT + t0 + w * 16 + l15) * k3C + h * kHD + quad * 8;
            async16(g0,      &Pf[(w * 2 + 0) * 512]);
            async16(g0 + 32, &Pf[(w * 2 + 1) * 512]);
        }
        wait_vm0();   // own-wave DMA drained; Pf region is wave-private
        const bf16x8 aq0 = *(const bf16x8*)&Pf[(w * 2 + 0) * 512 + lane * 8];
        const bf16x8 aq1 = *(const bf16x8*)&Pf[(w * 2 + 1) * 512 + lane * 8];

        float m_run[4], l_run[4];
        f32x4 acc_o[4];
        #pragma unroll
        for (int r = 0; r < 4; ++r) { m_run[r] = -INFINITY; l_run[r] = 0.f; }
        #pragma unroll
        for (int n = 0; n < 4; ++n) {
            f32x4 z = {0.f, 0.f, 0.f, 0.f};
            acc_o[n] = z;
        }

        for (int c = 0; c < nchunks; ++c) {
            const int kbase = c * 64;
            const int buf = c & 1;
            wait_vm0();        // drain stage(c) (issued prev iter / phase top)
            __syncthreads();   // all waves' parts visible; prev buffer free
            if (c + 1 < nchunks) stage(1 - buf, kbase + 64);  // prefetch

            // S = Q K^T  (D[m=q][n=key]); 8 MFMAs.
            f32x4 acc_s[4];
            #pragma unroll
            for (int k = 0; k < 4; ++k) {
                f32x4 z = {0.f, 0.f, 0.f, 0.f};
                acc_s[k] = z;
            }
            #pragma unroll
            for (int ksub = 0; ksub < 4; ++ksub) {
                const bf16x8 bk0 =
                    *(const bf16x8*)&Kf[buf][(ksub * 2 + 0) * 512 + lane * 8];
                const bf16x8 bk1 =
                    *(const bf16x8*)&Kf[buf][(ksub * 2 + 1) * 512 + lane * 8];
                acc_s[ksub] = __builtin_amdgcn_mfma_f32_16x16x32_bf16(
                    aq0, bk0, acc_s[ksub], 0, 0, 0);
                acc_s[ksub] = __builtin_amdgcn_mfma_f32_16x16x32_bf16(
                    aq1, bk1, acc_s[ksub], 0, 0, 0);
            }

            // Scale + causal mask (diagonal chunk only).
            float sv[4][4];   // [ksub][r]
            #pragma unroll
            for (int ksub = 0; ksub < 4; ++ksub)
                #pragma unroll
                for (int r = 0; r < 4; ++r)
                    sv[ksub][r] = acc_s[ksub][r] * 0.125f;
            if (kbase == t0) {
                const int qrow = t0 + w * 16 + quad * 4;   // + r
                #pragma unroll
                for (int ksub = 0; ksub < 4; ++ksub) {
                    const int key = kbase + ksub * 16 + l15;
                    #pragma unroll
                    for (int r = 0; r < 4; ++r)
                        if (key > qrow + r) sv[ksub][r] = -INFINITY;
                }
            }

            // Online softmax; row r stats shared by the 16 lanes of a quad.
            float alpha[4];
            #pragma unroll
            for (int r = 0; r < 4; ++r) {
                float mx = fmaxf(fmaxf(sv[0][r], sv[1][r]),
                                 fmaxf(sv[2][r], sv[3][r]));
                mx = fmaxf(mx, __shfl_xor(mx, 1));
                mx = fmaxf(mx, __shfl_xor(mx, 2));
                mx = fmaxf(mx, __shfl_xor(mx, 4));
                mx = fmaxf(mx, __shfl_xor(mx, 8));
                const float m_new = fmaxf(m_run[r], mx);
                alpha[r] = __expf(m_run[r] - m_new);  // 1st chunk: exp(-inf)=0
                float ps = 0.f;
                #pragma unroll
                for (int ksub = 0; ksub < 4; ++ksub) {
                    sv[ksub][r] = __expf(sv[ksub][r] - m_new);
                    ps += sv[ksub][r];
                }
                ps += __shfl_xor(ps, 1);
                ps += __shfl_xor(ps, 2);
                ps += __shfl_xor(ps, 4);
                ps += __shfl_xor(ps, 8);
                l_run[r] = l_run[r] * alpha[r] + ps;
                m_run[r] = m_new;
            }

            // Scatter P (bf16) into wave-private A-frag layout (same-wave
            // DS ordering: no barrier between this write and the read).
            #pragma unroll
            for (int ksub = 0; ksub < 4; ++ksub) {
                const int key = ksub * 16 + l15;
                #pragma unroll
                for (int r = 0; r < 4; ++r) {
                    const int lp = quad * 4 + r + ((key & 31) >> 3) * 16;
                    Pf[(w * 2 + (key >> 5)) * 512 + lp * 8 + (key & 7)] =
                        f2bf(sv[ksub][r]);
                }
            }

            // O = O*alpha + P V  (D[m=q][n=d]); 8 MFMAs.
            #pragma unroll
            for (int n = 0; n < 4; ++n)
                #pragma unroll
                for (int r = 0; r < 4; ++r)
                    acc_o[n][r] *= alpha[r];
            const bf16x8 ap0 = *(const bf16x8*)&Pf[(w * 2 + 0) * 512 + lane * 8];
            const bf16x8 ap1 = *(const bf16x8*)&Pf[(w * 2 + 1) * 512 + lane * 8];
            #pragma unroll
            for (int nsub = 0; nsub < 4; ++nsub) {
                const bf16x8 bv0 =
                    *(const bf16x8*)&Vf[buf][(nsub * 2 + 0) * 512 + lane * 8];
                const bf16x8 bv1 =
                    *(const bf16x8*)&Vf[buf][(nsub * 2 + 1) * 512 + lane * 8];
                acc_o[nsub] = __builtin_amdgcn_mfma_f32_16x16x32_bf16(
                    ap0, bv0, acc_o[nsub], 0, 0, 0);
                acc_o[nsub] = __builtin_amdgcn_mfma_f32_16x16x32_bf16(
                    ap1, bv1, acc_o[nsub], 0, 0, 0);
            }
        }

        // y = O / l (bf16).  C-layout: col=l15 (d), rows quad*4+r.
        float inv[4];
        #pragma unroll
        for (int r = 0; r < 4; ++r) inv[r] = 1.0f / l_run[r];
        #pragma unroll
        for (int nsub = 0; nsub < 4; ++nsub)
            #pragma unroll
            for (int r = 0; r < 4; ++r)
                y[(size_t)(b * kT + t0 + w * 16 + quad * 4 + r) * kC +
                  h * kHD + nsub * 16 + l15] = f2bf(acc_o[nsub][r] * inv[r]);
    }
}

extern "C" void kernel_launch(void* const* d_in, const int* in_sizes, int n_in,
                              void* d_out, int out_size, void* d_ws, size_t ws_size,
                              hipStream_t stream) {
    const float* x      = (const float*)d_in[0];
    const float* w_attn = (const float*)d_in[1];
    const float* b_attn = (const float*)d_in[2];
    const float* w_proj = (const float*)d_in[3];
    const float* b_proj = (const float*)d_in[4];
    float* out = (float*)d_out;

    // Workspace (bf16, 64.5 MiB): VT overlays xb (same element count;
    // xb is dead after GEMM1, VT created after GEMM1 — stream-ordered).
    unsigned short* xb     = (unsigned short*)d_ws;           // [8192][768]
    unsigned short* VT     = xb;                              // [96][64][1024]
    unsigned short* wattnT = xb     + (size_t)kM * kC;        // [2304][768]
    unsigned short* wprojT = wattnT + (size_t)k3C * kC;       // [768][768]
    unsigned short* qkv    = wprojT + (size_t)kC * kC;        // [8192][2304]
    unsigned short* yb     = qkv    + (size_t)kM * k3C;       // [8192][768]

    // Pre-passes: cast x; transpose+cast weights to [N][K].
    cvt_bf16_kernel<<<(kM * kC) / (4 * 256), 256, 0, stream>>>(x, xb);
    transpose_cvt_kernel<<<dim3(k3C / 32, kC / 32), 256, 0, stream>>>(
        w_attn, wattnT, kC, k3C);
    transpose_cvt_kernel<<<dim3(kC / 32, kC / 32), 256, 0, stream>>>(
        w_proj, wprojT, kC, kC);

    // 1) QKV projection: xb[8192,768] @ wattnT^T + b_attn -> qkv (bf16)
    //    Grid 36x64 = 2304 blocks = 9.0/CU (uniform).
    gemm_mfma_kernel<true><<<dim3(k3C / 64, kM / 128), 256, 0, stream>>>(
        xb, kC, wattnT, b_attn, qkv, k3C, kC);

    // 1b) V^T pre-pass: qkv V columns -> VT[bh][d][t] (overwrites xb)
    vtrans_kernel<<<kB * kNH * (kT / 64), 256, 0, stream>>>(qkv, VT);

    // 2) MFMA causal attention (paired q-tiles, uniform blocks) -> yb
    attn_mfma_kernel<<<kB * kNH * 8, 256, 0, stream>>>(qkv, VT, yb);

    // 3) Output projection: yb @ wprojT^T + b_proj -> out (fp32)
    //    Grid 12x64 = 768 blocks = 3.0/CU (uniform).
    gemm_mfma_kernel<false><<<dim3(kC / 64, kM / 128), 256, 0, stream>>>(
        yb, kC, wprojT, b_proj, out, kC, kC);
}

// Round 10
// 242.828 us; speedup vs baseline: 1.0940x; 1.0940x over previous
//
#include <hip/hip_runtime.h>

// Problem constants (B,T,C,NH fixed by the reference).
constexpr int kB  = 8;
constexpr int kT  = 1024;
constexpr int kC  = 768;
constexpr int kNH = 12;
constexpr int kHD = 64;          // C/NH
constexpr int kM  = kB * kT;     // 8192 rows
constexpr int k3C = 3 * kC;      // 2304

using bf16x8 = __attribute__((ext_vector_type(8))) __bf16;
using f32x4  = __attribute__((ext_vector_type(4))) float;

__device__ __forceinline__ float bf2f(unsigned short u) {
    union { unsigned int i; float f; } v;
    v.i = ((unsigned int)u) << 16;
    return v.f;
}

// fp32 -> bf16 round-to-nearest-even.
__device__ __forceinline__ unsigned short f2bf(float f) {
    union { float f; unsigned int u; } v; v.f = f;
    unsigned int r = v.u + 0x7fffu + ((v.u >> 16) & 1u);
    return (unsigned short)(r >> 16);
}

// Async global->LDS, 16 B/lane. LDS arg must be the wave-uniform base; HW
// writes lane i at base + i*16 (m104/m108).
__device__ __forceinline__ void async16(const void* g, void* l) {
    __builtin_amdgcn_global_load_lds(
        (__attribute__((address_space(1))) void*)g,
        (__attribute__((address_space(3))) void*)l, 16, 0, 0);
}

// Explicit LDS-DMA drain (round-5 determinism fix — keep).
// imm: vmcnt[3:0]=0 (+[15:14]=0), expcnt[6:4]=7, lgkmcnt[11:8]=15.
__device__ __forceinline__ void wait_vm0() {
    __builtin_amdgcn_s_waitcnt(0x0F70);
}

// ---------------- pre-passes ----------------

// fp32 -> bf16 elementwise (n divisible by 4*256).
__global__ __launch_bounds__(256) void cvt_bf16_kernel(
    const float* __restrict__ in, unsigned short* __restrict__ out)
{
    const int i = blockIdx.x * 256 + threadIdx.x;
    const float4 v = ((const float4*)in)[i];
    ushort4 o;
    o.x = f2bf(v.x); o.y = f2bf(v.y); o.z = f2bf(v.z); o.w = f2bf(v.w);
    ((ushort4*)out)[i] = o;
}

// W[K][N] fp32 -> Wt[N][K] bf16.  Grid (N/32, K/32), block 256 (32x8).
__global__ __launch_bounds__(256) void transpose_cvt_kernel(
    const float* __restrict__ W, unsigned short* __restrict__ Wt, int K, int N)
{
    __shared__ float tile[32][33];
    const int tx = threadIdx.x & 31, ty = threadIdx.x >> 5;
    const int n0 = blockIdx.x * 32, k0 = blockIdx.y * 32;
    #pragma unroll
    for (int i = 0; i < 4; ++i)
        tile[ty + i * 8][tx] = W[(size_t)(k0 + ty + i * 8) * N + n0 + tx];
    __syncthreads();
    #pragma unroll
    for (int i = 0; i < 4; ++i)
        Wt[(size_t)(n0 + ty + i * 8) * K + k0 + tx] = f2bf(tile[tx][ty + i * 8]);
}

// V columns of qkv -> VT[bh][d][t] (bf16).  One block = 64t x 64d of one
// (b,h).  Grid 96*16.
__global__ __launch_bounds__(256) void vtrans_kernel(
    const unsigned short* __restrict__ qkv, unsigned short* __restrict__ VT)
{
    __shared__ unsigned short tile[64][72];   // 144 B rows (16B-aligned)
    const int tid = threadIdx.x;
    const int bh = blockIdx.x >> 4;
    const int b = bh / kNH, h = bh % kNH;
    const int tt = (blockIdx.x & 15) * 64;
    const int row = tid >> 2;
    const int c0  = (tid & 3) * 16;
    const unsigned short* src =
        qkv + (size_t)(b * kT + tt + row) * k3C + 2 * kC + h * kHD + c0;
    *(uint4*)&tile[row][c0]     = *(const uint4*)src;
    *(uint4*)&tile[row][c0 + 8] = *(const uint4*)(src + 8);
    __syncthreads();
    const int d  = tid >> 2;
    const int t8 = (tid & 3) * 16;
    unsigned short tmp[16];
    #pragma unroll
    for (int i = 0; i < 16; ++i) tmp[i] = tile[t8 + i][d];
    unsigned short* dst = VT + ((size_t)bh * kHD + d) * kT + tt + t8;
    *(uint4*)dst       = *(uint4*)&tmp[0];
    *(uint4*)(dst + 8) = *(uint4*)&tmp[8];
}

// ---------------- MFMA GEMM (double-buffered K-loop) ----------------
// out[M,N] = A[M,K](bf16, row stride lda) @ Bt[N,K](bf16)^T + bias(fp32).
// Round-10: BK=32, 2 LDS buffers, ONE barrier per K-iter with prefetch of
// iter+1 issued right after the barrier (round-7 attention transform).
// Rationale: round-9 post-mortem — the bottleneck is the serial
// stage->vmcnt(0)->barrier chain, not resident-block count; give the
// loads a full iteration of compute to fly.  Tile = 128 x (NSUB*16):
//   NSUB=8 -> 128x128 (gemm1, grid 18x64, LDS 32 KB, 5 blocks/CU)
//   NSUB=4 -> 128x64  (gemm2, grid 12x64 uniform 3/CU, LDS 24 KB)
// 4 waves in 2x2; wave = 64 x (NSUB*8) via acc[4][NSUB/2].
template<int NSUB, bool OUT_BF16>
__global__ __launch_bounds__(256) void gemm_mfma_kernel(
    const unsigned short* __restrict__ A, int lda,
    const unsigned short* __restrict__ Bt,
    const float* __restrict__ bias,
    void* __restrict__ outv, int N, int K)
{
    constexpr int NW = NSUB / 2;    // n-subtiles per wave
    constexpr int BB = NSUB / 4;    // B frags staged per wave (2 or 1)
    alignas(16) __shared__ unsigned short As[2][8 * 512];
    alignas(16) __shared__ unsigned short Bs[2][NSUB * 512];

    const int tid  = threadIdx.x;
    const int w    = tid >> 6;
    const int lane = tid & 63;
    const int wr = w >> 1, wc = w & 1;
    const int m0 = blockIdx.y * 128, n0 = blockIdx.x * (NSUB * 16);

    const int fr = lane & 15;            // row within 16-row subtile
    const int fk = (lane >> 4) * 8;      // k offset within 32-k subtile

    // Stage the 32-k tile at column kt into buffer bufi.
    auto stage = [&](int bufi, int kt) {
        #pragma unroll
        for (int t = 0; t < 2; ++t) {
            const int fa = w * 2 + t;            // A subtile 0..7
            const unsigned short* ga =
                A + (size_t)(m0 + fa * 16 + fr) * lda + kt + fk;
            async16(ga, &As[bufi][fa * 512]);    // wave-uniform LDS base
        }
        #pragma unroll
        for (int t = 0; t < BB; ++t) {
            const int fb = w * BB + t;           // B subtile 0..NSUB-1
            const unsigned short* gb =
                Bt + (size_t)(n0 + fb * 16 + fr) * K + kt + fk;
            async16(gb, &Bs[bufi][fb * 512]);
        }
    };

    f32x4 acc[4][NW];
    #pragma unroll
    for (int i = 0; i < 4; ++i)
        #pragma unroll
        for (int j = 0; j < NW; ++j) {
            f32x4 z = {0.f, 0.f, 0.f, 0.f};
            acc[i][j] = z;
        }

    stage(0, 0);
    const int niter = K / 32;
    for (int it = 0; it < niter; ++it) {
        const int buf = it & 1;
        wait_vm0();        // drain stage(it) (issued prev iter / preloop)
        __syncthreads();   // all waves' parts visible; other buffer is free
        if (it + 1 < niter) stage(1 - buf, (it + 1) * 32);  // prefetch

        bf16x8 a[4], b[NW];
        #pragma unroll
        for (int i = 0; i < 4; ++i)
            a[i] = *(const bf16x8*)&As[buf][(wr * 4 + i) * 512 + lane * 8];
        #pragma unroll
        for (int j = 0; j < NW; ++j)
            b[j] = *(const bf16x8*)&Bs[buf][(wc * NW + j) * 512 + lane * 8];
        #pragma unroll
        for (int i = 0; i < 4; ++i)
            #pragma unroll
            for (int j = 0; j < NW; ++j)
                acc[i][j] = __builtin_amdgcn_mfma_f32_16x16x32_bf16(
                    a[i], b[j], acc[i][j], 0, 0, 0);
    }

    // Epilogue.  C/D: col = lane&15, row = (lane>>4)*4 + reg.
    const int quad  = lane >> 4;
    const int col16 = lane & 15;
    float biasv[NW];
    #pragma unroll
    for (int j = 0; j < NW; ++j)
        biasv[j] = bias[n0 + wc * (NW * 16) + j * 16 + col16];

    #pragma unroll
    for (int i = 0; i < 4; ++i) {
        #pragma unroll
        for (int r = 0; r < 4; ++r) {
            const int row = m0 + wr * 64 + i * 16 + quad * 4 + r;
            #pragma unroll
            for (int j = 0; j < NW; ++j) {
                const int col = n0 + wc * (NW * 16) + j * 16 + col16;
                const float v = acc[i][j][r] + biasv[j];
                if (OUT_BF16)
                    ((unsigned short*)outv)[(size_t)row * N + col] = f2bf(v);
                else
                    ((float*)outv)[(size_t)row * N + col] = v;
            }
        }
    }
}

// ---------------- MFMA flash attention (paired q-tiles) ----------------
// One block = q-tiles (15-pid, pid) of one (b,h): uniform 17-chunk cost.
// K/V dbuf prefetch, reg-Q, reg-softmax (rounds 6-8).
__global__ __launch_bounds__(256) void attn_mfma_kernel(
    const unsigned short* __restrict__ qkv,
    const unsigned short* __restrict__ VT,     // [96][64][1024]
    unsigned short* __restrict__ y)            // [8192][768]
{
    alignas(16) __shared__ unsigned short Kf[2][8 * 512];  // 16 KB
    alignas(16) __shared__ unsigned short Vf[2][8 * 512];  // 16 KB
    alignas(16) __shared__ unsigned short Pf[8 * 512];     // 8 KB, wave-private

    const int tid  = threadIdx.x;
    const int w    = tid >> 6;
    const int lane = tid & 63;
    const int quad = lane >> 4, l15 = lane & 15;
    const int bh  = blockIdx.x >> 3;
    const int b   = bh / kNH, h = bh % kNH;
    const int pid = blockIdx.x & 7;

    // Stage K frags (ksub=w) and V^T frags (nsub=w) for chunk kbase.
    auto stage = [&](int bufi, int kbase) {
        const unsigned short* gk = qkv +
            (size_t)(b * kT + kbase + w * 16 + l15) * k3C + kC + h * kHD + quad * 8;
        async16(gk,      &Kf[bufi][(w * 2 + 0) * 512]);
        async16(gk + 32, &Kf[bufi][(w * 2 + 1) * 512]);
        const unsigned short* gv = VT +
            ((size_t)bh * kHD + w * 16 + l15) * kT + kbase + quad * 8;
        async16(gv,      &Vf[bufi][(w * 2 + 0) * 512]);
        async16(gv + 32, &Vf[bufi][(w * 2 + 1) * 512]);
    };

    #pragma unroll 1
    for (int phase = 0; phase < 2; ++phase) {
        const int t0 = (phase == 0 ? (15 - pid) : pid) * 64;  // heavy first
        const int nchunks = t0 / 64 + 1;

        // WAR: all waves done reading K/V buffers from the previous phase
        // before we restage buffer 0. (Harmless extra barrier in phase 0.)
        __syncthreads();
        stage(0, 0);
        // Q staged once through Pf (wave-private region) -> registers.
        {
            const unsigned short* g0 = qkv +
                (size_t)(b * kT + t0 + w * 16 + l15) * k3C + h * kHD + quad * 8;
            async16(g0,      &Pf[(w * 2 + 0) * 512]);
            async16(g0 + 32, &Pf[(w * 2 + 1) * 512]);
        }
        wait_vm0();   // own-wave DMA drained; Pf region is wave-private
        const bf16x8 aq0 = *(const bf16x8*)&Pf[(w * 2 + 0) * 512 + lane * 8];
        const bf16x8 aq1 = *(const bf16x8*)&Pf[(w * 2 + 1) * 512 + lane * 8];

        float m_run[4], l_run[4];
        f32x4 acc_o[4];
        #pragma unroll
        for (int r = 0; r < 4; ++r) { m_run[r] = -INFINITY; l_run[r] = 0.f; }
        #pragma unroll
        for (int n = 0; n < 4; ++n) {
            f32x4 z = {0.f, 0.f, 0.f, 0.f};
            acc_o[n] = z;
        }

        for (int c = 0; c < nchunks; ++c) {
            const int kbase = c * 64;
            const int buf = c & 1;
            wait_vm0();        // drain stage(c) (issued prev iter / phase top)
            __syncthreads();   // all waves' parts visible; prev buffer free
            if (c + 1 < nchunks) stage(1 - buf, kbase + 64);  // prefetch

            // S = Q K^T  (D[m=q][n=key]); 8 MFMAs.
            f32x4 acc_s[4];
            #pragma unroll
            for (int k = 0; k < 4; ++k) {
                f32x4 z = {0.f, 0.f, 0.f, 0.f};
                acc_s[k] = z;
            }
            #pragma unroll
            for (int ksub = 0; ksub < 4; ++ksub) {
                const bf16x8 bk0 =
                    *(const bf16x8*)&Kf[buf][(ksub * 2 + 0) * 512 + lane * 8];
                const bf16x8 bk1 =
                    *(const bf16x8*)&Kf[buf][(ksub * 2 + 1) * 512 + lane * 8];
                acc_s[ksub] = __builtin_amdgcn_mfma_f32_16x16x32_bf16(
                    aq0, bk0, acc_s[ksub], 0, 0, 0);
                acc_s[ksub] = __builtin_amdgcn_mfma_f32_16x16x32_bf16(
                    aq1, bk1, acc_s[ksub], 0, 0, 0);
            }

            // Scale + causal mask (diagonal chunk only).
            float sv[4][4];   // [ksub][r]
            #pragma unroll
            for (int ksub = 0; ksub < 4; ++ksub)
                #pragma unroll
                for (int r = 0; r < 4; ++r)
                    sv[ksub][r] = acc_s[ksub][r] * 0.125f;
            if (kbase == t0) {
                const int qrow = t0 + w * 16 + quad * 4;   // + r
                #pragma unroll
                for (int ksub = 0; ksub < 4; ++ksub) {
                    const int key = kbase + ksub * 16 + l15;
                    #pragma unroll
                    for (int r = 0; r < 4; ++r)
                        if (key > qrow + r) sv[ksub][r] = -INFINITY;
                }
            }

            // Online softmax; row r stats shared by the 16 lanes of a quad.
            float alpha[4];
            #pragma unroll
            for (int r = 0; r < 4; ++r) {
                float mx = fmaxf(fmaxf(sv[0][r], sv[1][r]),
                                 fmaxf(sv[2][r], sv[3][r]));
                mx = fmaxf(mx, __shfl_xor(mx, 1));
                mx = fmaxf(mx, __shfl_xor(mx, 2));
                mx = fmaxf(mx, __shfl_xor(mx, 4));
                mx = fmaxf(mx, __shfl_xor(mx, 8));
                const float m_new = fmaxf(m_run[r], mx);
                alpha[r] = __expf(m_run[r] - m_new);  // 1st chunk: exp(-inf)=0
                float ps = 0.f;
                #pragma unroll
                for (int ksub = 0; ksub < 4; ++ksub) {
                    sv[ksub][r] = __expf(sv[ksub][r] - m_new);
                    ps += sv[ksub][r];
                }
                ps += __shfl_xor(ps, 1);
                ps += __shfl_xor(ps, 2);
                ps += __shfl_xor(ps, 4);
                ps += __shfl_xor(ps, 8);
                l_run[r] = l_run[r] * alpha[r] + ps;
                m_run[r] = m_new;
            }

            // Scatter P (bf16) into wave-private A-frag layout (same-wave
            // DS ordering: no barrier between this write and the read).
            #pragma unroll
            for (int ksub = 0; ksub < 4; ++ksub) {
                const int key = ksub * 16 + l15;
                #pragma unroll
                for (int r = 0; r < 4; ++r) {
                    const int lp = quad * 4 + r + ((key & 31) >> 3) * 16;
                    Pf[(w * 2 + (key >> 5)) * 512 + lp * 8 + (key & 7)] =
                        f2bf(sv[ksub][r]);
                }
            }

            // O = O*alpha + P V  (D[m=q][n=d]); 8 MFMAs.
            #pragma unroll
            for (int n = 0; n < 4; ++n)
                #pragma unroll
                for (int r = 0; r < 4; ++r)
                    acc_o[n][r] *= alpha[r];
            const bf16x8 ap0 = *(const bf16x8*)&Pf[(w * 2 + 0) * 512 + lane * 8];
            const bf16x8 ap1 = *(const bf16x8*)&Pf[(w * 2 + 1) * 512 + lane * 8];
            #pragma unroll
            for (int nsub = 0; nsub < 4; ++nsub) {
                const bf16x8 bv0 =
                    *(const bf16x8*)&Vf[buf][(nsub * 2 + 0) * 512 + lane * 8];
                const bf16x8 bv1 =
                    *(const bf16x8*)&Vf[buf][(nsub * 2 + 1) * 512 + lane * 8];
                acc_o[nsub] = __builtin_amdgcn_mfma_f32_16x16x32_bf16(
                    ap0, bv0, acc_o[nsub], 0, 0, 0);
                acc_o[nsub] = __builtin_amdgcn_mfma_f32_16x16x32_bf16(
                    ap1, bv1, acc_o[nsub], 0, 0, 0);
            }
        }

        // y = O / l (bf16).  C-layout: col=l15 (d), rows quad*4+r.
        float inv[4];
        #pragma unroll
        for (int r = 0; r < 4; ++r) inv[r] = 1.0f / l_run[r];
        #pragma unroll
        for (int nsub = 0; nsub < 4; ++nsub)
            #pragma unroll
            for (int r = 0; r < 4; ++r)
                y[(size_t)(b * kT + t0 + w * 16 + quad * 4 + r) * kC +
                  h * kHD + nsub * 16 + l15] = f2bf(acc_o[nsub][r] * inv[r]);
    }
}

extern "C" void kernel_launch(void* const* d_in, const int* in_sizes, int n_in,
                              void* d_out, int out_size, void* d_ws, size_t ws_size,
                              hipStream_t stream) {
    const float* x      = (const float*)d_in[0];
    const float* w_attn = (const float*)d_in[1];
    const float* b_attn = (const float*)d_in[2];
    const float* w_proj = (const float*)d_in[3];
    const float* b_proj = (const float*)d_in[4];
    float* out = (float*)d_out;

    // Workspace (bf16, 64.5 MiB): VT overlays xb (same element count;
    // xb is dead after GEMM1, VT created after GEMM1 — stream-ordered).
    unsigned short* xb     = (unsigned short*)d_ws;           // [8192][768]
    unsigned short* VT     = xb;                              // [96][64][1024]
    unsigned short* wattnT = xb     + (size_t)kM * kC;        // [2304][768]
    unsigned short* wprojT = wattnT + (size_t)k3C * kC;       // [768][768]
    unsigned short* qkv    = wprojT + (size_t)kC * kC;        // [8192][2304]
    unsigned short* yb     = qkv    + (size_t)kM * k3C;       // [8192][768]

    // Pre-passes: cast x; transpose+cast weights to [N][K].
    cvt_bf16_kernel<<<(kM * kC) / (4 * 256), 256, 0, stream>>>(x, xb);
    transpose_cvt_kernel<<<dim3(k3C / 32, kC / 32), 256, 0, stream>>>(
        w_attn, wattnT, kC, k3C);
    transpose_cvt_kernel<<<dim3(kC / 32, kC / 32), 256, 0, stream>>>(
        w_proj, wprojT, kC, kC);

    // 1) QKV projection: xb[8192,768] @ wattnT^T + b_attn -> qkv (bf16)
    //    128x128 dbuf tile: grid 18x64 = 1152 blocks.
    gemm_mfma_kernel<8, true><<<dim3(k3C / 128, kM / 128), 256, 0, stream>>>(
        xb, kC, wattnT, b_attn, qkv, k3C, kC);

    // 1b) V^T pre-pass: qkv V columns -> VT[bh][d][t] (overwrites xb)
    vtrans_kernel<<<kB * kNH * (kT / 64), 256, 0, stream>>>(qkv, VT);

    // 2) MFMA causal attention (paired q-tiles, uniform blocks) -> yb
    attn_mfma_kernel<<<kB * kNH * 8, 256, 0, stream>>>(qkv, VT, yb);

    // 3) Output projection: yb @ wprojT^T + b_proj -> out (fp32)
    //    128x64 dbuf tile: grid 12x64 = 768 blocks (3.0/CU uniform).
    gemm_mfma_kernel<4, false><<<dim3(kC / 64, kM / 128), 256, 0, stream>>>(
        yb, kC, wprojT, b_proj, out, kC, kC);
}

// Round 11
// 236.821 us; speedup vs baseline: 1.1217x; 1.0254x over previous
//
#include <hip/hip_runtime.h>

// Problem constants (B,T,C,NH fixed by the reference).
constexpr int kB  = 8;
constexpr int kT  = 1024;
constexpr int kC  = 768;
constexpr int kNH = 12;
constexpr int kHD = 64;          // C/NH
constexpr int kM  = kB * kT;     // 8192 rows
constexpr int k3C = 3 * kC;      // 2304
constexpr int kQK = 2 * kC;      // 1536: qkv2 row stride (Q,K only; V -> VT)

using bf16x8 = __attribute__((ext_vector_type(8))) __bf16;
using f32x4  = __attribute__((ext_vector_type(4))) float;

// fp32 -> bf16 round-to-nearest-even.
__device__ __forceinline__ unsigned short f2bf(float f) {
    union { float f; unsigned int u; } v; v.f = f;
    unsigned int r = v.u + 0x7fffu + ((v.u >> 16) & 1u);
    return (unsigned short)(r >> 16);
}

// Async global->LDS, 16 B/lane. LDS arg must be the wave-uniform base; HW
// writes lane i at base + i*16 (m104/m108).
__device__ __forceinline__ void async16(const void* g, void* l) {
    __builtin_amdgcn_global_load_lds(
        (__attribute__((address_space(1))) void*)g,
        (__attribute__((address_space(3))) void*)l, 16, 0, 0);
}

// s_waitcnt with compile-time imm.  exp=7, lgkm=15 (don't wait), vmcnt=N:
// imm = 0x0F70 | N (N<16).  Rounds 5-10 established that LDS-DMA reads
// ordered after this builtin are correct (no hoisting observed).
template<int IMM> __device__ __forceinline__ void wait_vm() {
    __builtin_amdgcn_s_waitcnt(IMM);
}
__device__ __forceinline__ void wait_vm0() { __builtin_amdgcn_s_waitcnt(0x0F70); }

// ---------------- pre-passes ----------------

// fp32 -> bf16 elementwise (n divisible by 4*256).
__global__ __launch_bounds__(256) void cvt_bf16_kernel(
    const float* __restrict__ in, unsigned short* __restrict__ out)
{
    const int i = blockIdx.x * 256 + threadIdx.x;
    const float4 v = ((const float4*)in)[i];
    ushort4 o;
    o.x = f2bf(v.x); o.y = f2bf(v.y); o.z = f2bf(v.z); o.w = f2bf(v.w);
    ((ushort4*)out)[i] = o;
}

// W[K][N] fp32 -> Wt[N][K] bf16.  Grid (N/32, K/32), block 256 (32x8).
__global__ __launch_bounds__(256) void transpose_cvt_kernel(
    const float* __restrict__ W, unsigned short* __restrict__ Wt, int K, int N)
{
    __shared__ float tile[32][33];
    const int tx = threadIdx.x & 31, ty = threadIdx.x >> 5;
    const int n0 = blockIdx.x * 32, k0 = blockIdx.y * 32;
    #pragma unroll
    for (int i = 0; i < 4; ++i)
        tile[ty + i * 8][tx] = W[(size_t)(k0 + ty + i * 8) * N + n0 + tx];
    __syncthreads();
    #pragma unroll
    for (int i = 0; i < 4; ++i)
        Wt[(size_t)(n0 + ty + i * 8) * K + k0 + tx] = f2bf(tile[tx][ty + i * 8]);
}

// ---------------- MFMA GEMM (3-stage pipelined K-loop) ----------------
// out = A[M,K](bf16, row stride lda) @ Bt[N,K](bf16)^T + bias(fp32).
// Round-11: 3 LDS stages, prefetch distance 2, fine s_waitcnt vmcnt(P) +
// RAW s_barrier (no implicit vmcnt(0) drain — __syncthreads emits one,
// which capped prefetch distance at ~1 compute window in rounds 9/10;
// profile showed ~8k cyc/iter vs ~300 issue, i.e. latency-starved).
// Safety: each wave drains its own stage(it) DMAs (vmcnt(P) leaves only
// stage(it+1) in flight) BEFORE the barrier, so post-barrier all waves'
// stage(it) parts are visible.  Buffer (it+2)%3 is WAR-safe: its readers
// ran in iter it-1, which every wave finished before this barrier.
// MODE 0: fp32 out (gemm2).  MODE 1 (gemm1): bf16 out, N-blocks < 12
// write qkv2[8192][1536] (Q,K); blocks 12..17 write VT[bh][d][t] directly
// from accumulators (vtrans pass eliminated).
template<int NSUB, int MODE>
__global__ __launch_bounds__(256) void gemm_mfma_kernel(
    const unsigned short* __restrict__ A, int lda,
    const unsigned short* __restrict__ Bt,
    const float* __restrict__ bias,
    void* __restrict__ outv,
    unsigned short* __restrict__ vt,   // MODE 1 only
    int N, int K)
{
    constexpr int NW = NSUB / 2;                 // n-subtiles per wave
    constexpr int BB = (NSUB / 4 > 0) ? NSUB / 4 : 1;  // B frags/wave/stage
    constexpr int P  = 2 + BB;                   // own DMAs per stage
    constexpr int WAIT_P = 0x0F70 | P;

    alignas(16) __shared__ unsigned short As[3][8 * 512];
    alignas(16) __shared__ unsigned short Bs[3][NSUB * 512];

    const int tid  = threadIdx.x;
    const int w    = tid >> 6;
    const int lane = tid & 63;
    const int wr = w >> 1, wc = w & 1;
    const int m0 = blockIdx.y * 128, n0 = blockIdx.x * (NSUB * 16);

    const int fr = lane & 15;            // row within 16-row subtile
    const int fk = (lane >> 4) * 8;      // k offset within 32-k subtile

    auto stage = [&](int bufi, int kt) {
        #pragma unroll
        for (int t = 0; t < 2; ++t) {
            const int fa = w * 2 + t;            // A subtile 0..7
            const unsigned short* ga =
                A + (size_t)(m0 + fa * 16 + fr) * lda + kt + fk;
            async16(ga, &As[bufi][fa * 512]);    // wave-uniform LDS base
        }
        #pragma unroll
        for (int t = 0; t < BB; ++t) {
            const int fb = w * BB + t;           // B subtile 0..NSUB-1
            const unsigned short* gb =
                Bt + (size_t)(n0 + fb * 16 + fr) * K + kt + fk;
            async16(gb, &Bs[bufi][fb * 512]);
        }
    };

    f32x4 acc[4][NW];
    #pragma unroll
    for (int i = 0; i < 4; ++i)
        #pragma unroll
        for (int j = 0; j < NW; ++j) {
            f32x4 z = {0.f, 0.f, 0.f, 0.f};
            acc[i][j] = z;
        }

    const int niter = K / 32;          // 24 for K=768
    stage(0, 0);
    stage(1, 32);
    int cur = 0, pf = 2;
    for (int it = 0; it < niter; ++it) {
        if (it + 1 < niter) wait_vm<WAIT_P>();   // stage(it) done, (it+1) flying
        else               wait_vm<0x0F70>();    // last iter: drain all
        __builtin_amdgcn_s_barrier();            // raw: no implicit drain
        if (it + 2 < niter) stage(pf, (it + 2) * 32);

        bf16x8 a[4], b[NW];
        #pragma unroll
        for (int i = 0; i < 4; ++i)
            a[i] = *(const bf16x8*)&As[cur][(wr * 4 + i) * 512 + lane * 8];
        #pragma unroll
        for (int j = 0; j < NW; ++j)
            b[j] = *(const bf16x8*)&Bs[cur][(wc * NW + j) * 512 + lane * 8];
        #pragma unroll
        for (int i = 0; i < 4; ++i)
            #pragma unroll
            for (int j = 0; j < NW; ++j)
                acc[i][j] = __builtin_amdgcn_mfma_f32_16x16x32_bf16(
                    a[i], b[j], acc[i][j], 0, 0, 0);

        cur = (cur == 2) ? 0 : cur + 1;
        pf  = (pf  == 2) ? 0 : pf  + 1;
    }

    // Epilogue.  C/D: col = lane&15, row = (lane>>4)*4 + reg.
    const int quad  = lane >> 4;
    const int col16 = lane & 15;
    float biasv[NW];
    #pragma unroll
    for (int j = 0; j < NW; ++j)
        biasv[j] = bias[n0 + wc * (NW * 16) + j * 16 + col16];

    if (MODE == 1 && n0 >= kQK) {
        // V region -> VT[bh][d][t], 4 consecutive t per (i,j) -> ushort4.
        const int bidx = m0 >> 10;               // batch (128 | 1024)
        #pragma unroll
        for (int i = 0; i < 4; ++i) {
            const int row = m0 + wr * 64 + i * 16 + quad * 4;
            const int t = row & 1023;
            #pragma unroll
            for (int j = 0; j < NW; ++j) {
                const int hv = n0 + wc * (NW * 16) + j * 16 + col16 - kQK;
                const int h = hv >> 6, d = hv & 63;
                ushort4 o;
                o.x = f2bf(acc[i][j][0] + biasv[j]);
                o.y = f2bf(acc[i][j][1] + biasv[j]);
                o.z = f2bf(acc[i][j][2] + biasv[j]);
                o.w = f2bf(acc[i][j][3] + biasv[j]);
                *(ushort4*)&vt[((size_t)(bidx * kNH + h) * kHD + d) * kT + t] = o;
            }
        }
    } else {
        #pragma unroll
        for (int i = 0; i < 4; ++i) {
            #pragma unroll
            for (int r = 0; r < 4; ++r) {
                const int row = m0 + wr * 64 + i * 16 + quad * 4 + r;
                #pragma unroll
                for (int j = 0; j < NW; ++j) {
                    const int col = n0 + wc * (NW * 16) + j * 16 + col16;
                    const float v = acc[i][j][r] + biasv[j];
                    if (MODE == 1)
                        ((unsigned short*)outv)[(size_t)row * kQK + col] = f2bf(v);
                    else
                        ((float*)outv)[(size_t)row * N + col] = v;
                }
            }
        }
    }
}

// ---------------- MFMA flash attention (paired q-tiles) ----------------
// One block = q-tiles (15-pid, pid) of one (b,h): uniform 17-chunk cost.
// K/V dbuf prefetch, reg-Q, reg-softmax (rounds 6-8).  Reads qkv2
// (stride 1536: Q at +0, K at +768) and VT[bh][d][t].
__global__ __launch_bounds__(256) void attn_mfma_kernel(
    const unsigned short* __restrict__ qkv2,
    const unsigned short* __restrict__ VT,     // [96][64][1024]
    unsigned short* __restrict__ y)            // [8192][768]
{
    alignas(16) __shared__ unsigned short Kf[2][8 * 512];  // 16 KB
    alignas(16) __shared__ unsigned short Vf[2][8 * 512];  // 16 KB
    alignas(16) __shared__ unsigned short Pf[8 * 512];     // 8 KB, wave-private

    const int tid  = threadIdx.x;
    const int w    = tid >> 6;
    const int lane = tid & 63;
    const int quad = lane >> 4, l15 = lane & 15;
    const int bh  = blockIdx.x >> 3;
    const int b   = bh / kNH, h = bh % kNH;
    const int pid = blockIdx.x & 7;

    auto stage = [&](int bufi, int kbase) {
        const unsigned short* gk = qkv2 +
            (size_t)(b * kT + kbase + w * 16 + l15) * kQK + kC + h * kHD + quad * 8;
        async16(gk,      &Kf[bufi][(w * 2 + 0) * 512]);
        async16(gk + 32, &Kf[bufi][(w * 2 + 1) * 512]);
        const unsigned short* gv = VT +
            ((size_t)bh * kHD + w * 16 + l15) * kT + kbase + quad * 8;
        async16(gv,      &Vf[bufi][(w * 2 + 0) * 512]);
        async16(gv + 32, &Vf[bufi][(w * 2 + 1) * 512]);
    };

    #pragma unroll 1
    for (int phase = 0; phase < 2; ++phase) {
        const int t0 = (phase == 0 ? (15 - pid) : pid) * 64;  // heavy first
        const int nchunks = t0 / 64 + 1;

        __syncthreads();   // prev-phase buffer reads complete
        stage(0, 0);
        {
            const unsigned short* g0 = qkv2 +
                (size_t)(b * kT + t0 + w * 16 + l15) * kQK + h * kHD + quad * 8;
            async16(g0,      &Pf[(w * 2 + 0) * 512]);
            async16(g0 + 32, &Pf[(w * 2 + 1) * 512]);
        }
        wait_vm0();   // own-wave DMA drained; Pf region is wave-private
        const bf16x8 aq0 = *(const bf16x8*)&Pf[(w * 2 + 0) * 512 + lane * 8];
        const bf16x8 aq1 = *(const bf16x8*)&Pf[(w * 2 + 1) * 512 + lane * 8];

        float m_run[4], l_run[4];
        f32x4 acc_o[4];
        #pragma unroll
        for (int r = 0; r < 4; ++r) { m_run[r] = -INFINITY; l_run[r] = 0.f; }
        #pragma unroll
        for (int n = 0; n < 4; ++n) {
            f32x4 z = {0.f, 0.f, 0.f, 0.f};
            acc_o[n] = z;
        }

        for (int c = 0; c < nchunks; ++c) {
            const int kbase = c * 64;
            const int buf = c & 1;
            wait_vm0();        // drain stage(c)
            __syncthreads();
            if (c + 1 < nchunks) stage(1 - buf, kbase + 64);  // prefetch

            f32x4 acc_s[4];
            #pragma unroll
            for (int k = 0; k < 4; ++k) {
                f32x4 z = {0.f, 0.f, 0.f, 0.f};
                acc_s[k] = z;
            }
            #pragma unroll
            for (int ksub = 0; ksub < 4; ++ksub) {
                const bf16x8 bk0 =
                    *(const bf16x8*)&Kf[buf][(ksub * 2 + 0) * 512 + lane * 8];
                const bf16x8 bk1 =
                    *(const bf16x8*)&Kf[buf][(ksub * 2 + 1) * 512 + lane * 8];
                acc_s[ksub] = __builtin_amdgcn_mfma_f32_16x16x32_bf16(
                    aq0, bk0, acc_s[ksub], 0, 0, 0);
                acc_s[ksub] = __builtin_amdgcn_mfma_f32_16x16x32_bf16(
                    aq1, bk1, acc_s[ksub], 0, 0, 0);
            }

            float sv[4][4];   // [ksub][r]
            #pragma unroll
            for (int ksub = 0; ksub < 4; ++ksub)
                #pragma unroll
                for (int r = 0; r < 4; ++r)
                    sv[ksub][r] = acc_s[ksub][r] * 0.125f;
            if (kbase == t0) {
                const int qrow = t0 + w * 16 + quad * 4;   // + r
                #pragma unroll
                for (int ksub = 0; ksub < 4; ++ksub) {
                    const int key = kbase + ksub * 16 + l15;
                    #pragma unroll
                    for (int r = 0; r < 4; ++r)
                        if (key > qrow + r) sv[ksub][r] = -INFINITY;
                }
            }

            float alpha[4];
            #pragma unroll
            for (int r = 0; r < 4; ++r) {
                float mx = fmaxf(fmaxf(sv[0][r], sv[1][r]),
                                 fmaxf(sv[2][r], sv[3][r]));
                mx = fmaxf(mx, __shfl_xor(mx, 1));
                mx = fmaxf(mx, __shfl_xor(mx, 2));
                mx = fmaxf(mx, __shfl_xor(mx, 4));
                mx = fmaxf(mx, __shfl_xor(mx, 8));
                const float m_new = fmaxf(m_run[r], mx);
                alpha[r] = __expf(m_run[r] - m_new);  // 1st chunk: exp(-inf)=0
                float ps = 0.f;
                #pragma unroll
                for (int ksub = 0; ksub < 4; ++ksub) {
                    sv[ksub][r] = __expf(sv[ksub][r] - m_new);
                    ps += sv[ksub][r];
                }
                ps += __shfl_xor(ps, 1);
                ps += __shfl_xor(ps, 2);
                ps += __shfl_xor(ps, 4);
                ps += __shfl_xor(ps, 8);
                l_run[r] = l_run[r] * alpha[r] + ps;
                m_run[r] = m_new;
            }

            #pragma unroll
            for (int ksub = 0; ksub < 4; ++ksub) {
                const int key = ksub * 16 + l15;
                #pragma unroll
                for (int r = 0; r < 4; ++r) {
                    const int lp = quad * 4 + r + ((key & 31) >> 3) * 16;
                    Pf[(w * 2 + (key >> 5)) * 512 + lp * 8 + (key & 7)] =
                        f2bf(sv[ksub][r]);
                }
            }

            #pragma unroll
            for (int n = 0; n < 4; ++n)
                #pragma unroll
                for (int r = 0; r < 4; ++r)
                    acc_o[n][r] *= alpha[r];
            const bf16x8 ap0 = *(const bf16x8*)&Pf[(w * 2 + 0) * 512 + lane * 8];
            const bf16x8 ap1 = *(const bf16x8*)&Pf[(w * 2 + 1) * 512 + lane * 8];
            #pragma unroll
            for (int nsub = 0; nsub < 4; ++nsub) {
                const bf16x8 bv0 =
                    *(const bf16x8*)&Vf[buf][(nsub * 2 + 0) * 512 + lane * 8];
                const bf16x8 bv1 =
                    *(const bf16x8*)&Vf[buf][(nsub * 2 + 1) * 512 + lane * 8];
                acc_o[nsub] = __builtin_amdgcn_mfma_f32_16x16x32_bf16(
                    ap0, bv0, acc_o[nsub], 0, 0, 0);
                acc_o[nsub] = __builtin_amdgcn_mfma_f32_16x16x32_bf16(
                    ap1, bv1, acc_o[nsub], 0, 0, 0);
            }
        }

        float inv[4];
        #pragma unroll
        for (int r = 0; r < 4; ++r) inv[r] = 1.0f / l_run[r];
        #pragma unroll
        for (int nsub = 0; nsub < 4; ++nsub)
            #pragma unroll
            for (int r = 0; r < 4; ++r)
                y[(size_t)(b * kT + t0 + w * 16 + quad * 4 + r) * kC +
                  h * kHD + nsub * 16 + l15] = f2bf(acc_o[nsub][r] * inv[r]);
    }
}

extern "C" void kernel_launch(void* const* d_in, const int* in_sizes, int n_in,
                              void* d_out, int out_size, void* d_ws, size_t ws_size,
                              hipStream_t stream) {
    const float* x      = (const float*)d_in[0];
    const float* w_attn = (const float*)d_in[1];
    const float* b_attn = (const float*)d_in[2];
    const float* w_proj = (const float*)d_in[3];
    const float* b_proj = (const float*)d_in[4];
    float* out = (float*)d_out;

    // Workspace (bf16, ~67.6 MiB; round 2 used 75.5 successfully):
    unsigned short* xb     = (unsigned short*)d_ws;           // [8192][768]
    unsigned short* wattnT = xb     + (size_t)kM * kC;        // [2304][768]
    unsigned short* wprojT = wattnT + (size_t)k3C * kC;       // [768][768]
    unsigned short* qkv2   = wprojT + (size_t)kC * kC;        // [8192][1536]
    unsigned short* VT     = qkv2   + (size_t)kM * kQK;       // [96][64][1024]
    unsigned short* yb     = VT     + (size_t)kNH * kB * kHD * kT; // [8192][768]

    // Pre-passes: cast x; transpose+cast weights to [N][K].
    cvt_bf16_kernel<<<(kM * kC) / (4 * 256), 256, 0, stream>>>(x, xb);
    transpose_cvt_kernel<<<dim3(k3C / 32, kC / 32), 256, 0, stream>>>(
        w_attn, wattnT, kC, k3C);
    transpose_cvt_kernel<<<dim3(kC / 32, kC / 32), 256, 0, stream>>>(
        w_proj, wprojT, kC, kC);

    // 1) QKV projection: Q,K -> qkv2 (stride 1536); V -> VT (fused
    //    transpose in epilogue).  Grid 18x64, 3-stage pipelined K-loop.
    gemm_mfma_kernel<8, 1><<<dim3(k3C / 128, kM / 128), 256, 0, stream>>>(
        xb, kC, wattnT, b_attn, qkv2, VT, k3C, kC);

    // 2) MFMA causal attention (paired q-tiles, uniform blocks) -> yb
    attn_mfma_kernel<<<kB * kNH * 8, 256, 0, stream>>>(qkv2, VT, yb);

    // 3) Output projection: yb @ wprojT^T + b_proj -> out (fp32).
    //    Grid 12x64 uniform, 3-stage pipelined K-loop.
    gemm_mfma_kernel<4, 0><<<dim3(kC / 64, kM / 128), 256, 0, stream>>>(
        yb, kC, wprojT, b_proj, out, nullptr, kC, kC);
}